// Round 7
// baseline (16342.500 us; speedup 1.0000x reference)
//
#include <hip/hip_runtime.h>
#include <math.h>

#define N_PTS 8192
#define M_PTS 2048
#define NM_PTS 10240
#define D_DIM 768
#define EPS_F 0.0025f
#define INV_EPS_F 400.0f
#define SINK_ITERS 50
#define QSCALE_F 12800.0f     // u16 units: (C/eps)*32  (step 1/32 nat)
#define R8_STEP_F 0.375f      // u8 residual step in nats = 12 u16 units
#define U16_TO_NAT 0.03125f
#define PERS_BLOCKS 256

typedef __attribute__((ext_vector_type(8))) short short8;
typedef __attribute__((ext_vector_type(4))) float f32x4;

// Q8 / QT8 rows stored PERMUTED per 2048-col segment (r5-validated):
// byte position p = 32L + 4t + e holds logical column c = 256t + 4L + e,
// so lane L reads bytes [32L..32L+32) and bias floats hb4[64t + lane].

// ---------------------------------------------------------------------------
__device__ __forceinline__ unsigned short sk_f2bf(float f)
{
    const unsigned u = __float_as_uint(f);
    return (unsigned short)((u + 0x7fffu + ((u >> 16) & 1u)) >> 16);
}

__device__ __forceinline__ void sk_merge(float& m, float& s, float mc, float sc)
{
    const float nm = fmaxf(m, mc);
    s = s * __expf(m - nm) + sc * __expf(mc - nm);
    m = nm;
}

__device__ __forceinline__ void sk_z4(unsigned int w, const float* hbr, int o, float* z)
{
    z[o + 0] = fmaf((float)(w & 0xffu),         -R8_STEP_F, hbr[o + 0]);
    z[o + 1] = fmaf((float)((w >> 8) & 0xffu),  -R8_STEP_F, hbr[o + 1]);
    z[o + 2] = fmaf((float)((w >> 16) & 0xffu), -R8_STEP_F, hbr[o + 2]);
    z[o + 3] = fmaf((float)(w >> 24),           -R8_STEP_F, hbr[o + 3]);
}

__device__ __forceinline__ void sk_lse32(
    const uint4 q0, const uint4 q1, const float* hbr, float& mc, float& sc)
{
    float z[32];
    sk_z4(q0.x, hbr, 0, z);  sk_z4(q0.y, hbr, 4, z);
    sk_z4(q0.z, hbr, 8, z);  sk_z4(q0.w, hbr, 12, z);
    sk_z4(q1.x, hbr, 16, z); sk_z4(q1.y, hbr, 20, z);
    sk_z4(q1.z, hbr, 24, z); sk_z4(q1.w, hbr, 28, z);
    mc = z[0];
    #pragma unroll
    for (int k = 1; k < 32; ++k) mc = fmaxf(mc, z[k]);
    sc = 0.f;
    #pragma unroll
    for (int k = 0; k < 32; ++k) sc += __expf(z[k] - mc);
}

// ---------------------------------------------------------------------------
// init: LW = (log h | log hi), hbF = log hi (g=0), R32 = INT_MAX, ctrl = 0
// ---------------------------------------------------------------------------
__global__ __launch_bounds__(256) void sk_init(
    const float* __restrict__ h, const float* __restrict__ hi,
    float* __restrict__ lw, float* __restrict__ hbF, int* __restrict__ r32,
    int* __restrict__ ctrl)
{
    const int t = blockIdx.x * 256 + threadIdx.x;
    if (t < N_PTS) { lw[t] = logf(h[t]); r32[t] = 0x7fffffff; }
    else if (t < NM_PTS) {
        const float v = logf(hi[t - N_PTS]);
        lw[t] = v; hbF[t - N_PTS] = v;
    }
    if (t < 8192) ctrl[t] = 0;
}

// ---------------------------------------------------------------------------
__global__ __launch_bounds__(256) void sk_cast(
    const float* __restrict__ src, unsigned short* __restrict__ dst)
{
    const int t = blockIdx.x * 256 + threadIdx.x;
    const float4 v = ((const float4*)src)[t];
    ushort4 o;
    o.x = sk_f2bf(v.x); o.y = sk_f2bf(v.y); o.z = sk_f2bf(v.z); o.w = sk_f2bf(v.w);
    ((ushort4*)dst)[t] = o;
}

// ---------------------------------------------------------------------------
// MFMA bf16 NT-GEMM, 128x128 tile, 256 thr (r5-validated form).
// MODE 0: Xb = bf16(dot) via LDS-transpose epilogue.
// MODE 1: q = sat_u16(relu(xs+ys-dot)*12800); column-packed QTu16 stores +
//         per-row atomicMin -> R32.
// ---------------------------------------------------------------------------
template<int MODE>
__global__ __launch_bounds__(256) void sk_mfma(
    const unsigned short* __restrict__ A, const unsigned short* __restrict__ B,
    unsigned short* __restrict__ Xb,
    unsigned short* __restrict__ QT, int* __restrict__ R32,
    const float* __restrict__ xs, const float* __restrict__ ys)
{
    constexpr int LS = 40;
    __shared__ unsigned short As[128 * LS];
    __shared__ unsigned short Bs[128 * LS];
    __shared__ int rmin[128];
    const int tid  = threadIdx.x;
    const int wave = tid >> 6, lane = tid & 63;
    const int quad = lane >> 4, l16 = lane & 15;
    const int row0 = blockIdx.y * 128, col0 = blockIdx.x * 128;
    const int wr = (wave >> 1) * 64, wc = (wave & 1) * 64;
    if (MODE == 1 && tid < 128) rmin[tid] = 0x7fffffff;

    const int sr = tid >> 2;
    const int sk = (tid & 3) * 8;
    const unsigned short* Ap  = A + (size_t)(row0 + sr) * D_DIM + sk;
    const unsigned short* Ap2 = Ap + (size_t)64 * D_DIM;
    const unsigned short* Bp  = B + (size_t)(col0 + sr) * D_DIM + sk;
    const unsigned short* Bp2 = Bp + (size_t)64 * D_DIM;

    f32x4 acc[4][4] = {};

    for (int k0 = 0; k0 < D_DIM; k0 += 32) {
        const short8 a0 = *(const short8*)(Ap + k0);
        const short8 a1 = *(const short8*)(Ap2 + k0);
        const short8 b0 = *(const short8*)(Bp + k0);
        const short8 b1 = *(const short8*)(Bp2 + k0);
        __syncthreads();
        *(short8*)(As + sr * LS + sk)        = a0;
        *(short8*)(As + (sr + 64) * LS + sk) = a1;
        *(short8*)(Bs + sr * LS + sk)        = b0;
        *(short8*)(Bs + (sr + 64) * LS + sk) = b1;
        __syncthreads();
        short8 af[4], bfr[4];
        #pragma unroll
        for (int i = 0; i < 4; ++i) {
            af[i]  = *(const short8*)(As + (wr + i * 16 + l16) * LS + quad * 8);
            bfr[i] = *(const short8*)(Bs + (wc + i * 16 + l16) * LS + quad * 8);
        }
        #pragma unroll
        for (int i = 0; i < 4; ++i)
            #pragma unroll
            for (int j = 0; j < 4; ++j)
                acc[i][j] = __builtin_amdgcn_mfma_f32_16x16x32_bf16(
                    af[i], bfr[j], acc[i][j], 0, 0, 0);
    }

    if (MODE == 0) {
        unsigned short* sl = As;
        const int sgrp = wr >> 6;
        const int osg = tid >> 7, orow = (tid >> 3) & 15, oc16 = (tid & 7) * 16;
        #pragma unroll
        for (int i = 0; i < 4; ++i) {
            __syncthreads();
            #pragma unroll
            for (int j = 0; j < 4; ++j)
                #pragma unroll
                for (int r = 0; r < 4; ++r)
                    sl[sgrp * 2176 + (quad * 4 + r) * 136 + wc + j * 16 + l16] =
                        sk_f2bf(acc[i][j][r]);
            __syncthreads();
            const unsigned short* src = sl + osg * 2176 + orow * 136 + oc16;
            const short8 v0 = *(const short8*)src;
            const short8 v1 = *(const short8*)(src + 8);
            unsigned short* dst = Xb +
                (size_t)(row0 + osg * 64 + i * 16 + orow) * D_DIM + col0 + oc16;
            *(short8*)dst = v0;
            *(short8*)(dst + 8) = v1;
        }
    } else {
        const int gm0 = row0 + wr + quad * 4;
        const int gn0 = col0 + wc + l16;
        #pragma unroll
        for (int i = 0; i < 4; ++i) {
            float xv[4];
            #pragma unroll
            for (int r = 0; r < 4; ++r) xv[r] = xs[gm0 + i * 16 + r];
            int qmn[4] = {0x7fffffff, 0x7fffffff, 0x7fffffff, 0x7fffffff};
            #pragma unroll
            for (int j = 0; j < 4; ++j) {
                const int gn = gn0 + j * 16;
                const float ysv = ys[gn];
                unsigned short q4[4];
                #pragma unroll
                for (int r = 0; r < 4; ++r) {
                    const float c = fmaxf(xv[r] + ysv - acc[i][j][r], 0.f);
                    const int iq = (int)fminf(fmaf(c, QSCALE_F, 0.5f), 65535.f);
                    qmn[r] = min(qmn[r], iq);
                    q4[r] = (unsigned short)iq;
                }
                *(ushort4*)(QT + (size_t)gn * N_PTS + gm0 + i * 16) =
                    *(const ushort4*)q4;
            }
            #pragma unroll
            for (int r = 0; r < 4; ++r)
                atomicMin(&rmin[wr + i * 16 + quad * 4 + r], qmn[r]);
        }
        __syncthreads();
        if (tid < 128) atomicMin(&R32[row0 + tid], rmin[tid]);
    }
}

// ---------------------------------------------------------------------------
__global__ __launch_bounds__(256) void sk_row_norms(
    const unsigned short* __restrict__ Xb, float* __restrict__ XS)
{
    const int row  = blockIdx.x * 4 + (threadIdx.x >> 6);
    const int lane = threadIdx.x & 63;
    const unsigned int* p = (const unsigned int*)(Xb + (size_t)row * D_DIM);
    float s = 0.f;
    #pragma unroll
    for (int k = 0; k < 6; ++k) {
        const unsigned int u = p[lane + k * 64];
        const float f0 = __uint_as_float(u << 16);
        const float f1 = __uint_as_float(u & 0xffff0000u);
        s = fmaf(f0, f0, s); s = fmaf(f1, f1, s);
    }
    #pragma unroll
    for (int off = 32; off; off >>= 1) s += __shfl_xor(s, off, 64);
    if (lane == 0) XS[row] = 0.5f * s;
}

// ---------------------------------------------------------------------------
// QTu16 -> Q8 (transpose + permute + u8 requant vs R32[i])  (r5-validated)
// ---------------------------------------------------------------------------
__global__ __launch_bounds__(256) void sk_transq(
    const unsigned short* __restrict__ QT, const int* __restrict__ R32,
    unsigned char* __restrict__ Q8)
{
    __shared__ unsigned short tile[64][72];
    const int tid = threadIdx.x;
    const int J0 = blockIdx.x * 64;
    const int I0 = blockIdx.y * 64;
    {
        const int tj = tid >> 2, ti = (tid & 3) * 16;
        const uint4* src = (const uint4*)(QT + (size_t)(J0 + tj) * N_PTS + I0 + ti);
        const uint4 a = src[0], b = src[1];
        *(uint4*)&tile[tj][ti] = a;
        *(uint4*)&tile[tj][ti + 8] = b;
    }
    __syncthreads();
    const int li = tid >> 2, lj = (tid & 3) * 16;
    const int R = R32[I0 + li];
    const int L0 = (J0 >> 2) & 63;
    const int t0 = J0 >> 8;
    unsigned char* orow = Q8 + (size_t)(I0 + li) * M_PTS;
    #pragma unroll
    for (int q = 0; q < 4; ++q) {
        unsigned char ob[4];
        #pragma unroll
        for (int e = 0; e < 4; ++e) {
            const int qv = (int)tile[lj + q * 4 + e][li];
            ob[e] = (unsigned char)fminf(fmaf((float)(qv - R), 1.0f / 12.0f, 0.5f), 255.f);
        }
        *(unsigned int*)(orow + 32 * (L0 + (lj >> 2) + q) + 4 * t0) =
            *(const unsigned int*)ob;
    }
}

// ---------------------------------------------------------------------------
// QTu16 -> QT8 (permuted per segment, u8 requant vs R32[i]) (r5-validated)
// ---------------------------------------------------------------------------
__global__ __launch_bounds__(256) void sk_requant_qt(
    const unsigned short* __restrict__ QT, const int* __restrict__ R32,
    unsigned char* __restrict__ QT8)
{
    const size_t base = ((size_t)blockIdx.x * 256 + threadIdx.x) * 16;
    const int i0 = (int)(base & (size_t)(N_PTS - 1));
    const size_t rowb = base & ~(size_t)(N_PTS - 1);
    const uint4* src = (const uint4*)(QT + base);
    const uint4 a = src[0], b = src[1];
    unsigned int qs[8] = {a.x, a.y, a.z, a.w, b.x, b.y, b.z, b.w};
    const int* rp = R32 + i0;
    const int s  = i0 >> 11;
    const int ip = i0 & 2047;
    const int t  = ip >> 8;
    const int L0 = (ip >> 2) & 63;
    unsigned char* orow = QT8 + rowb + 2048 * s + 4 * t;
    #pragma unroll
    for (int q = 0; q < 4; ++q) {
        unsigned char ob[4];
        #pragma unroll
        for (int e = 0; e < 4; ++e) {
            const int k = q * 4 + e;
            const int qv = (int)((qs[k >> 1] >> ((k & 1) * 16)) & 0xffffu);
            ob[e] = (unsigned char)fminf(fmaf((float)(qv - rp[k]), 1.0f / 12.0f, 0.5f), 255.f);
        }
        *(unsigned int*)(orow + 32 * (L0 + q)) = *(const unsigned int*)ob;
    }
}

// ---------------------------------------------------------------------------
// Flat grid barrier: per-phase monotone counter (stride-64 ints). Leader-only
// arrival (release add) + relaxed spin; per-thread threadfence on both sides
// for device-scope store visibility (cross-XCD L2 non-coherence).
// ---------------------------------------------------------------------------
__device__ __forceinline__ void sk_gbar(int* cnt, const int p)
{
    __threadfence();
    __syncthreads();
    if (threadIdx.x == 0) {
        __hip_atomic_fetch_add(&cnt[p * 64], 1, __ATOMIC_RELEASE,
                               __HIP_MEMORY_SCOPE_AGENT);
        while (__hip_atomic_load(&cnt[p * 64], __ATOMIC_RELAXED,
                                 __HIP_MEMORY_SCOPE_AGENT) < PERS_BLOCKS)
            __builtin_amdgcn_s_sleep(8);
    }
    __syncthreads();
    __threadfence();
}

// ---------------------------------------------------------------------------
// Persistent Sinkhorn: all 50 iterations + final extrapolation + finalize in
// ONE dispatch (256 blocks x 1024 thr, co-resident via cooperative launch).
// F phase: 32 rows/block (2 rows/wave);  G phase: 8 rows/block
// (2 rows x 1 segment per wave, LDS merge).  101 internal barriers.
// ---------------------------------------------------------------------------
__global__ __launch_bounds__(1024, 4) void sk_sink_pers(
    const unsigned char* __restrict__ Q8,
    const unsigned char* __restrict__ QT8,
    const float* __restrict__ LW, const int* __restrict__ R32,
    float* __restrict__ hbF, float* __restrict__ hbG, float* __restrict__ FO,
    const float* __restrict__ h, const float* __restrict__ hi,
    int* __restrict__ cnt, float* __restrict__ out)
{
    __shared__ float mred[4][4][2], sred[4][4][2];
    __shared__ float fred[1024];
    const int tid = threadIdx.x, wave = tid >> 6, lane = tid & 63;
    const int b = blockIdx.x;
    int phase = 0;

    for (int it = 0; it <= SINK_ITERS; ++it) {
        // ---------------- F phase ----------------
        {
            const int row0 = b * 32 + wave * 2;
            const uint4* qp0 = (const uint4*)(Q8 + (size_t)row0 * M_PTS);
            const uint4* qp1 = (const uint4*)(Q8 + (size_t)(row0 + 1) * M_PTS);
            const uint4 a0 = qp0[lane * 2], a1 = qp0[lane * 2 + 1];
            const uint4 b0 = qp1[lane * 2], b1 = qp1[lane * 2 + 1];
            float hbr[32];
            const float4* hb4 = (const float4*)hbF;
            #pragma unroll
            for (int t = 0; t < 8; ++t) {
                const float4 v = hb4[t * 64 + lane];
                hbr[t * 4 + 0] = v.x; hbr[t * 4 + 1] = v.y;
                hbr[t * 4 + 2] = v.z; hbr[t * 4 + 3] = v.w;
            }
            float m0, s0, m1, s1;
            sk_lse32(a0, a1, hbr, m0, s0);
            sk_lse32(b0, b1, hbr, m1, s1);
            #pragma unroll
            for (int off = 1; off < 64; off <<= 1) {
                float mm = __shfl_xor(m0, off, 64), ss = __shfl_xor(s0, off, 64);
                sk_merge(m0, s0, mm, ss);
                mm = __shfl_xor(m1, off, 64); ss = __shfl_xor(s1, off, 64);
                sk_merge(m1, s1, mm, ss);
            }
            if (lane == 0) {
                const float lse0 = m0 + __logf(s0);
                const float lse1 = m1 + __logf(s1);
                if (it == SINK_ITERS) {
                    FO[row0]     = EPS_F * ((float)R32[row0] * U16_TO_NAT - lse0);
                    FO[row0 + 1] = EPS_F * ((float)R32[row0 + 1] * U16_TO_NAT - lse1);
                } else {
                    hbG[row0]     = LW[row0] - lse0;
                    hbG[row0 + 1] = LW[row0 + 1] - lse1;
                }
            }
        }
        sk_gbar(cnt, phase++);
        if (it == SINK_ITERS) break;

        // ---------------- G phase ----------------
        {
            const int p   = wave >> 2;      // 0..3 row pair
            const int seg = wave & 3;       // 2048-col segment
            const int row0 = b * 8 + p * 2;
            float hbr[32];
            const float4* hb4 = (const float4*)hbG;
            #pragma unroll
            for (int t = 0; t < 8; ++t) {
                const float4 v = hb4[seg * 512 + t * 64 + lane];
                hbr[t * 4 + 0] = v.x; hbr[t * 4 + 1] = v.y;
                hbr[t * 4 + 2] = v.z; hbr[t * 4 + 3] = v.w;
            }
            const uint4* qp0 = (const uint4*)(QT8 + (size_t)row0 * N_PTS);
            const uint4* qp1 = (const uint4*)(QT8 + (size_t)(row0 + 1) * N_PTS);
            const uint4 a0 = qp0[seg * 128 + lane * 2];
            const uint4 a1 = qp0[seg * 128 + lane * 2 + 1];
            const uint4 b0 = qp1[seg * 128 + lane * 2];
            const uint4 b1 = qp1[seg * 128 + lane * 2 + 1];
            float m0, s0, m1, s1;
            sk_lse32(a0, a1, hbr, m0, s0);
            sk_lse32(b0, b1, hbr, m1, s1);
            #pragma unroll
            for (int off = 1; off < 64; off <<= 1) {
                float mm = __shfl_xor(m0, off, 64), ss = __shfl_xor(s0, off, 64);
                sk_merge(m0, s0, mm, ss);
                mm = __shfl_xor(m1, off, 64); ss = __shfl_xor(s1, off, 64);
                sk_merge(m1, s1, mm, ss);
            }
            if (lane == 0) {
                mred[p][seg][0] = m0; sred[p][seg][0] = s0;
                mred[p][seg][1] = m1; sred[p][seg][1] = s1;
            }
            __syncthreads();
            if (seg == 0 && lane < 2) {
                float m = mred[p][0][lane], s = sred[p][0][lane];
                #pragma unroll
                for (int g = 1; g < 4; ++g)
                    sk_merge(m, s, mred[p][g][lane], sred[p][g][lane]);
                const int row = row0 + lane;
                hbF[row] = LW[N_PTS + row] - (m + __logf(s));
            }
        }
        sk_gbar(cnt, phase++);
    }

    // ---------------- finalize (block 0) ----------------
    if (b == 0) {
        float acc = 0.f;
        for (int r = tid; r < N_PTS; r += 1024)
            acc += h[r] * (FO[r] + 0.5f * EPS_F * LW[r]);
        for (int j = tid; j < M_PTS; j += 1024)
            acc += hi[j] * EPS_F * (hbF[j] - 0.5f * LW[N_PTS + j]);
        fred[tid] = acc;
        __syncthreads();
        for (int st = 512; st; st >>= 1) {
            if (tid < st) fred[tid] += fred[tid + st];
            __syncthreads();
        }
        if (tid == 0) out[0] = expf(-fred[0]);
    }
}

// ---------------------------------------------------------------------------
extern "C" void kernel_launch(void* const* d_in, const int* in_sizes, int n_in,
                              void* d_out, int out_size, void* d_ws, size_t ws_size,
                              hipStream_t stream)
{
    const float* dpts = (const float*)d_in[0];
    const float* spts = (const float*)d_in[1];
    const float* h    = (const float*)d_in[2];
    const float* hiw  = (const float*)d_in[3];
    const float* W    = (const float*)d_in[4];
    float* out = (float*)d_out;

    float* XS  = (float*)d_ws;                        // NM
    float* LW  = XS + NM_PTS;                         // NM (la | lb)
    float* HBF = LW + NM_PTS;                         // M
    float* HBG = HBF + M_PTS;                         // N
    float* FO  = HBG + N_PTS;                         // N
    int*   R32 = (int*)(FO + N_PTS);                  // N
    int*   CT  = R32 + N_PTS;                         // 8192 ints (phase counters)
    unsigned short* Db = (unsigned short*)(CT + 8192);          // NM x D bf16
    unsigned short* Wb = Db + (size_t)NM_PTS * D_DIM;           // D x D bf16
    unsigned short* Xb = Wb + (size_t)D_DIM * D_DIM;            // NM x D bf16
    unsigned short* QTu = Xb + (size_t)NM_PTS * D_DIM;          // M x N u16
    unsigned char*  Q8  = (unsigned char*)(QTu + (size_t)M_PTS * N_PTS); // N x M u8
    unsigned char*  QT8 = Q8 + (size_t)N_PTS * M_PTS;           // M x N u8

    sk_init<<<NM_PTS / 256, 256, 0, stream>>>(h, hiw, LW, HBF, R32, CT);

    sk_cast<<<(size_t)N_PTS * D_DIM / 1024, 256, 0, stream>>>(dpts, Db);
    sk_cast<<<(size_t)M_PTS * D_DIM / 1024, 256, 0, stream>>>(
        spts, Db + (size_t)N_PTS * D_DIM);
    sk_cast<<<(size_t)D_DIM * D_DIM / 1024, 256, 0, stream>>>(W, Wb);

    sk_mfma<0><<<dim3(D_DIM / 128, NM_PTS / 128), 256, 0, stream>>>(
        Db, Wb, Xb, nullptr, nullptr, nullptr, nullptr);

    sk_row_norms<<<NM_PTS / 4, 256, 0, stream>>>(Xb, XS);

    sk_mfma<1><<<dim3(M_PTS / 128, N_PTS / 128), 256, 0, stream>>>(
        Xb, Xb + (size_t)N_PTS * D_DIM, nullptr, QTu, R32, XS, XS + N_PTS);

    sk_transq<<<dim3(M_PTS / 64, N_PTS / 64), 256, 0, stream>>>(QTu, R32, Q8);
    sk_requant_qt<<<(size_t)M_PTS * N_PTS / 4096, 256, 0, stream>>>(QTu, R32, QT8);

    {
        void* args[] = { (void*)&Q8, (void*)&QT8, (void*)&LW, (void*)&R32,
                         (void*)&HBF, (void*)&HBG, (void*)&FO,
                         (void*)&h, (void*)&hiw, (void*)&CT, (void*)&out };
        hipLaunchCooperativeKernel(sk_sink_pers, dim3(PERS_BLOCKS), dim3(1024),
                                   args, 0, stream);
    }
}

// Round 8
// 1527.540 us; speedup vs baseline: 10.6986x; 10.6986x over previous
//
#include <hip/hip_runtime.h>
#include <math.h>

#define N_PTS 8192
#define M_PTS 2048
#define NM_PTS 10240
#define D_DIM 768
#define EPS_F 0.0025f
#define INV_EPS_F 400.0f
#define SINK_ITERS 50
#define QSCALE_F 12800.0f     // u16 units: (C/eps)*32  (step 1/32 nat)
#define R8_STEP_F 0.375f      // u8 residual step in nats = 12 u16 units
#define U16_TO_NAT 0.03125f
#define PERS_BLOCKS 256
#define CTRL_STRIDE 160       // ints per phase: 8 group lines + root line

typedef __attribute__((ext_vector_type(8))) short short8;
typedef __attribute__((ext_vector_type(4))) float f32x4;

// Q8 / QT8 rows stored PERMUTED per 2048-col segment (r5-validated):
// byte position p = 32L + 4t + e holds logical column c = 256t + 4L + e.
//
// Round-8 coherence design (fix for r7's 16ms): NO fences anywhere in the
// persistent kernel. Communicated arrays (hbF/hbG/FO) use agent-scope
// relaxed atomic load/store (bypass non-coherent per-XCD L2, coherent at
// LLC). Immutable arrays (Q8/QT8/LW/R32) use plain cached loads and stay
// L2-resident across all 101 phases (r7's per-thread __threadfence L2
// invalidates caused 2.77GB refetch = 160us/phase).

// ---------------------------------------------------------------------------
__device__ __forceinline__ unsigned short sk_f2bf(float f)
{
    const unsigned u = __float_as_uint(f);
    return (unsigned short)((u + 0x7fffu + ((u >> 16) & 1u)) >> 16);
}

__device__ __forceinline__ void sk_merge(float& m, float& s, float mc, float sc)
{
    const float nm = fmaxf(m, mc);
    s = s * __expf(m - nm) + sc * __expf(mc - nm);
    m = nm;
}

__device__ __forceinline__ void sk_z4(unsigned int w, const float* hbr, int o, float* z)
{
    z[o + 0] = fmaf((float)(w & 0xffu),         -R8_STEP_F, hbr[o + 0]);
    z[o + 1] = fmaf((float)((w >> 8) & 0xffu),  -R8_STEP_F, hbr[o + 1]);
    z[o + 2] = fmaf((float)((w >> 16) & 0xffu), -R8_STEP_F, hbr[o + 2]);
    z[o + 3] = fmaf((float)(w >> 24),           -R8_STEP_F, hbr[o + 3]);
}

__device__ __forceinline__ void sk_lse32(
    const uint4 q0, const uint4 q1, const float* hbr, float& mc, float& sc)
{
    float z[32];
    sk_z4(q0.x, hbr, 0, z);  sk_z4(q0.y, hbr, 4, z);
    sk_z4(q0.z, hbr, 8, z);  sk_z4(q0.w, hbr, 12, z);
    sk_z4(q1.x, hbr, 16, z); sk_z4(q1.y, hbr, 20, z);
    sk_z4(q1.z, hbr, 24, z); sk_z4(q1.w, hbr, 28, z);
    mc = z[0];
    #pragma unroll
    for (int k = 1; k < 32; ++k) mc = fmaxf(mc, z[k]);
    sc = 0.f;
    #pragma unroll
    for (int k = 0; k < 32; ++k) sc += __expf(z[k] - mc);
}

// agent-scope helpers (coherent across XCDs, no cache maintenance)
__device__ __forceinline__ float sk_aload_f(const float* p)
{
    return __hip_atomic_load(p, __ATOMIC_RELAXED, __HIP_MEMORY_SCOPE_AGENT);
}
__device__ __forceinline__ unsigned long long sk_aload_u64(const void* p)
{
    return __hip_atomic_load((const unsigned long long*)p,
                             __ATOMIC_RELAXED, __HIP_MEMORY_SCOPE_AGENT);
}
__device__ __forceinline__ void sk_astore_f(float* p, float v)
{
    __hip_atomic_store(p, v, __ATOMIC_RELAXED, __HIP_MEMORY_SCOPE_AGENT);
}

// ---------------------------------------------------------------------------
// init: LW = (log h | log hi), hbF = log hi (g=0), R32 = INT_MAX, ctrl = 0
// ---------------------------------------------------------------------------
__global__ __launch_bounds__(256) void sk_init(
    const float* __restrict__ h, const float* __restrict__ hi,
    float* __restrict__ lw, float* __restrict__ hbF, int* __restrict__ r32,
    int* __restrict__ ctrl)
{
    const int t = blockIdx.x * 256 + threadIdx.x;
    if (t < N_PTS) { lw[t] = logf(h[t]); r32[t] = 0x7fffffff; }
    else if (t < NM_PTS) {
        const float v = logf(hi[t - N_PTS]);
        lw[t] = v; hbF[t - N_PTS] = v;
    }
    for (int k = t; k < 102 * CTRL_STRIDE; k += NM_PTS) ctrl[k] = 0;
}

// ---------------------------------------------------------------------------
__global__ __launch_bounds__(256) void sk_cast(
    const float* __restrict__ src, unsigned short* __restrict__ dst)
{
    const int t = blockIdx.x * 256 + threadIdx.x;
    const float4 v = ((const float4*)src)[t];
    ushort4 o;
    o.x = sk_f2bf(v.x); o.y = sk_f2bf(v.y); o.z = sk_f2bf(v.z); o.w = sk_f2bf(v.w);
    ((ushort4*)dst)[t] = o;
}

// ---------------------------------------------------------------------------
// MFMA bf16 NT-GEMM, 128x128 tile, 256 thr (r5-validated form).
// ---------------------------------------------------------------------------
template<int MODE>
__global__ __launch_bounds__(256) void sk_mfma(
    const unsigned short* __restrict__ A, const unsigned short* __restrict__ B,
    unsigned short* __restrict__ Xb,
    unsigned short* __restrict__ QT, int* __restrict__ R32,
    const float* __restrict__ xs, const float* __restrict__ ys)
{
    constexpr int LS = 40;
    __shared__ unsigned short As[128 * LS];
    __shared__ unsigned short Bs[128 * LS];
    __shared__ int rmin[128];
    const int tid  = threadIdx.x;
    const int wave = tid >> 6, lane = tid & 63;
    const int quad = lane >> 4, l16 = lane & 15;
    const int row0 = blockIdx.y * 128, col0 = blockIdx.x * 128;
    const int wr = (wave >> 1) * 64, wc = (wave & 1) * 64;
    if (MODE == 1 && tid < 128) rmin[tid] = 0x7fffffff;

    const int sr = tid >> 2;
    const int sk = (tid & 3) * 8;
    const unsigned short* Ap  = A + (size_t)(row0 + sr) * D_DIM + sk;
    const unsigned short* Ap2 = Ap + (size_t)64 * D_DIM;
    const unsigned short* Bp  = B + (size_t)(col0 + sr) * D_DIM + sk;
    const unsigned short* Bp2 = Bp + (size_t)64 * D_DIM;

    f32x4 acc[4][4] = {};

    for (int k0 = 0; k0 < D_DIM; k0 += 32) {
        const short8 a0 = *(const short8*)(Ap + k0);
        const short8 a1 = *(const short8*)(Ap2 + k0);
        const short8 b0 = *(const short8*)(Bp + k0);
        const short8 b1 = *(const short8*)(Bp2 + k0);
        __syncthreads();
        *(short8*)(As + sr * LS + sk)        = a0;
        *(short8*)(As + (sr + 64) * LS + sk) = a1;
        *(short8*)(Bs + sr * LS + sk)        = b0;
        *(short8*)(Bs + (sr + 64) * LS + sk) = b1;
        __syncthreads();
        short8 af[4], bfr[4];
        #pragma unroll
        for (int i = 0; i < 4; ++i) {
            af[i]  = *(const short8*)(As + (wr + i * 16 + l16) * LS + quad * 8);
            bfr[i] = *(const short8*)(Bs + (wc + i * 16 + l16) * LS + quad * 8);
        }
        #pragma unroll
        for (int i = 0; i < 4; ++i)
            #pragma unroll
            for (int j = 0; j < 4; ++j)
                acc[i][j] = __builtin_amdgcn_mfma_f32_16x16x32_bf16(
                    af[i], bfr[j], acc[i][j], 0, 0, 0);
    }

    if (MODE == 0) {
        unsigned short* sl = As;
        const int sgrp = wr >> 6;
        const int osg = tid >> 7, orow = (tid >> 3) & 15, oc16 = (tid & 7) * 16;
        #pragma unroll
        for (int i = 0; i < 4; ++i) {
            __syncthreads();
            #pragma unroll
            for (int j = 0; j < 4; ++j)
                #pragma unroll
                for (int r = 0; r < 4; ++r)
                    sl[sgrp * 2176 + (quad * 4 + r) * 136 + wc + j * 16 + l16] =
                        sk_f2bf(acc[i][j][r]);
            __syncthreads();
            const unsigned short* src = sl + osg * 2176 + orow * 136 + oc16;
            const short8 v0 = *(const short8*)src;
            const short8 v1 = *(const short8*)(src + 8);
            unsigned short* dst = Xb +
                (size_t)(row0 + osg * 64 + i * 16 + orow) * D_DIM + col0 + oc16;
            *(short8*)dst = v0;
            *(short8*)(dst + 8) = v1;
        }
    } else {
        const int gm0 = row0 + wr + quad * 4;
        const int gn0 = col0 + wc + l16;
        #pragma unroll
        for (int i = 0; i < 4; ++i) {
            float xv[4];
            #pragma unroll
            for (int r = 0; r < 4; ++r) xv[r] = xs[gm0 + i * 16 + r];
            int qmn[4] = {0x7fffffff, 0x7fffffff, 0x7fffffff, 0x7fffffff};
            #pragma unroll
            for (int j = 0; j < 4; ++j) {
                const int gn = gn0 + j * 16;
                const float ysv = ys[gn];
                unsigned short q4[4];
                #pragma unroll
                for (int r = 0; r < 4; ++r) {
                    const float c = fmaxf(xv[r] + ysv - acc[i][j][r], 0.f);
                    const int iq = (int)fminf(fmaf(c, QSCALE_F, 0.5f), 65535.f);
                    qmn[r] = min(qmn[r], iq);
                    q4[r] = (unsigned short)iq;
                }
                *(ushort4*)(QT + (size_t)gn * N_PTS + gm0 + i * 16) =
                    *(const ushort4*)q4;
            }
            #pragma unroll
            for (int r = 0; r < 4; ++r)
                atomicMin(&rmin[wr + i * 16 + quad * 4 + r], qmn[r]);
        }
        __syncthreads();
        if (tid < 128) atomicMin(&R32[row0 + tid], rmin[tid]);
    }
}

// ---------------------------------------------------------------------------
__global__ __launch_bounds__(256) void sk_row_norms(
    const unsigned short* __restrict__ Xb, float* __restrict__ XS)
{
    const int row  = blockIdx.x * 4 + (threadIdx.x >> 6);
    const int lane = threadIdx.x & 63;
    const unsigned int* p = (const unsigned int*)(Xb + (size_t)row * D_DIM);
    float s = 0.f;
    #pragma unroll
    for (int k = 0; k < 6; ++k) {
        const unsigned int u = p[lane + k * 64];
        const float f0 = __uint_as_float(u << 16);
        const float f1 = __uint_as_float(u & 0xffff0000u);
        s = fmaf(f0, f0, s); s = fmaf(f1, f1, s);
    }
    #pragma unroll
    for (int off = 32; off; off >>= 1) s += __shfl_xor(s, off, 64);
    if (lane == 0) XS[row] = 0.5f * s;
}

// ---------------------------------------------------------------------------
// QTu16 -> Q8 (transpose + permute + u8 requant vs R32[i])  (r5-validated)
// ---------------------------------------------------------------------------
__global__ __launch_bounds__(256) void sk_transq(
    const unsigned short* __restrict__ QT, const int* __restrict__ R32,
    unsigned char* __restrict__ Q8)
{
    __shared__ unsigned short tile[64][72];
    const int tid = threadIdx.x;
    const int J0 = blockIdx.x * 64;
    const int I0 = blockIdx.y * 64;
    {
        const int tj = tid >> 2, ti = (tid & 3) * 16;
        const uint4* src = (const uint4*)(QT + (size_t)(J0 + tj) * N_PTS + I0 + ti);
        const uint4 a = src[0], b = src[1];
        *(uint4*)&tile[tj][ti] = a;
        *(uint4*)&tile[tj][ti + 8] = b;
    }
    __syncthreads();
    const int li = tid >> 2, lj = (tid & 3) * 16;
    const int R = R32[I0 + li];
    const int L0 = (J0 >> 2) & 63;
    const int t0 = J0 >> 8;
    unsigned char* orow = Q8 + (size_t)(I0 + li) * M_PTS;
    #pragma unroll
    for (int q = 0; q < 4; ++q) {
        unsigned char ob[4];
        #pragma unroll
        for (int e = 0; e < 4; ++e) {
            const int qv = (int)tile[lj + q * 4 + e][li];
            ob[e] = (unsigned char)fminf(fmaf((float)(qv - R), 1.0f / 12.0f, 0.5f), 255.f);
        }
        *(unsigned int*)(orow + 32 * (L0 + (lj >> 2) + q) + 4 * t0) =
            *(const unsigned int*)ob;
    }
}

// ---------------------------------------------------------------------------
// QTu16 -> QT8 (permuted per segment, u8 requant vs R32[i]) (r5-validated)
// ---------------------------------------------------------------------------
__global__ __launch_bounds__(256) void sk_requant_qt(
    const unsigned short* __restrict__ QT, const int* __restrict__ R32,
    unsigned char* __restrict__ QT8)
{
    const size_t base = ((size_t)blockIdx.x * 256 + threadIdx.x) * 16;
    const int i0 = (int)(base & (size_t)(N_PTS - 1));
    const size_t rowb = base & ~(size_t)(N_PTS - 1);
    const uint4* src = (const uint4*)(QT + base);
    const uint4 a = src[0], b = src[1];
    unsigned int qs[8] = {a.x, a.y, a.z, a.w, b.x, b.y, b.z, b.w};
    const int* rp = R32 + i0;
    const int s  = i0 >> 11;
    const int ip = i0 & 2047;
    const int t  = ip >> 8;
    const int L0 = (ip >> 2) & 63;
    unsigned char* orow = QT8 + rowb + 2048 * s + 4 * t;
    #pragma unroll
    for (int q = 0; q < 4; ++q) {
        unsigned char ob[4];
        #pragma unroll
        for (int e = 0; e < 4; ++e) {
            const int k = q * 4 + e;
            const int qv = (int)((qs[k >> 1] >> ((k & 1) * 16)) & 0xffffu);
            ob[e] = (unsigned char)fminf(fmaf((float)(qv - rp[k]), 1.0f / 12.0f, 0.5f), 255.f);
        }
        *(unsigned int*)(orow + 32 * (L0 + q)) = *(const unsigned int*)ob;
    }
}

// ---------------------------------------------------------------------------
// Fence-free grid barrier. Per-phase monotone counters (no reset). Two-level
// arrival: 8 group lines (blockIdx&7) -> root line. Relaxed agent atomics
// only; store visibility comes from the vmcnt(0) drain each wave performs at
// __syncthreads (all communicated data uses agent-scope stores that are
// already coherent once complete). NO L2 invalidation.
// ---------------------------------------------------------------------------
__device__ __forceinline__ void sk_gbar(int* cnt, const int p)
{
    asm volatile("s_waitcnt vmcnt(0)" ::: "memory");
    __syncthreads();
    if (threadIdx.x == 0) {
        int* base = cnt + p * CTRL_STRIDE;
        const int g = blockIdx.x & 7;
        const int n = __hip_atomic_fetch_add(base + g * 16, 1,
                          __ATOMIC_RELAXED, __HIP_MEMORY_SCOPE_AGENT);
        if (n == (PERS_BLOCKS / 8) - 1)
            __hip_atomic_fetch_add(base + 128, 1, __ATOMIC_RELAXED,
                                   __HIP_MEMORY_SCOPE_AGENT);
        while (__hip_atomic_load(base + 128, __ATOMIC_RELAXED,
                                 __HIP_MEMORY_SCOPE_AGENT) < 8)
            __builtin_amdgcn_s_sleep(1);
    }
    __syncthreads();
}

// ---------------------------------------------------------------------------
// Persistent Sinkhorn: 50 iterations + extrapolation + finalize, ONE dispatch
// (256 blocks x 1024 thr, cooperative). F: 32 rows/block (2/wave).
// G: 8 rows/block (2 rows x 1 seg per wave, LDS merge). hb staged to LDS via
// 8-byte agent-scope loads each phase; hb writes are agent-scope stores.
// ---------------------------------------------------------------------------
__global__ __launch_bounds__(1024, 4) void sk_sink_pers(
    const unsigned char* __restrict__ Q8,
    const unsigned char* __restrict__ QT8,
    const float* __restrict__ LW, const int* __restrict__ R32,
    float* __restrict__ hbF, float* __restrict__ hbG, float* __restrict__ FO,
    const float* __restrict__ h, const float* __restrict__ hi,
    int* __restrict__ cnt, float* __restrict__ out)
{
    __shared__ float lds_hb[N_PTS];                 // 32 KB staging
    __shared__ float mred[4][4][2], sred[4][4][2];
    __shared__ float fred[1024];
    const int tid = threadIdx.x, wave = tid >> 6, lane = tid & 63;
    const int b = blockIdx.x;
    int phase = 0;

    // preload this block's immutable Q8 rows' base pointers
    const int frow0 = b * 32;
    const int grow0 = b * 8;

    for (int it = 0; it <= SINK_ITERS; ++it) {
        // ---------------- F phase (bias = hbF over M cols) ----------------
        {
            unsigned long long* lds64 = (unsigned long long*)lds_hb;
            lds64[tid] = sk_aload_u64((const unsigned long long*)hbF + tid);
            __syncthreads();
            const int row0 = frow0 + wave * 2;
            const uint4* qp0 = (const uint4*)(Q8 + (size_t)row0 * M_PTS);
            const uint4* qp1 = (const uint4*)(Q8 + (size_t)(row0 + 1) * M_PTS);
            const uint4 a0 = qp0[lane * 2], a1 = qp0[lane * 2 + 1];
            const uint4 b0 = qp1[lane * 2], b1 = qp1[lane * 2 + 1];
            float hbr[32];
            #pragma unroll
            for (int t = 0; t < 8; ++t) {
                const float4 v = *(const float4*)&lds_hb[(t * 64 + lane) * 4];
                hbr[t * 4 + 0] = v.x; hbr[t * 4 + 1] = v.y;
                hbr[t * 4 + 2] = v.z; hbr[t * 4 + 3] = v.w;
            }
            float m0, s0, m1, s1;
            sk_lse32(a0, a1, hbr, m0, s0);
            sk_lse32(b0, b1, hbr, m1, s1);
            #pragma unroll
            for (int off = 1; off < 64; off <<= 1) {
                float mm = __shfl_xor(m0, off, 64), ss = __shfl_xor(s0, off, 64);
                sk_merge(m0, s0, mm, ss);
                mm = __shfl_xor(m1, off, 64); ss = __shfl_xor(s1, off, 64);
                sk_merge(m1, s1, mm, ss);
            }
            if (lane == 0) {
                const float lse0 = m0 + __logf(s0);
                const float lse1 = m1 + __logf(s1);
                if (it == SINK_ITERS) {
                    sk_astore_f(&FO[row0],
                                EPS_F * ((float)R32[row0] * U16_TO_NAT - lse0));
                    sk_astore_f(&FO[row0 + 1],
                                EPS_F * ((float)R32[row0 + 1] * U16_TO_NAT - lse1));
                } else {
                    sk_astore_f(&hbG[row0],     LW[row0] - lse0);
                    sk_astore_f(&hbG[row0 + 1], LW[row0 + 1] - lse1);
                }
            }
        }
        sk_gbar(cnt, phase++);
        if (it == SINK_ITERS) break;

        // ---------------- G phase (bias = hbG over N cols) ----------------
        {
            unsigned long long* lds64 = (unsigned long long*)lds_hb;
            #pragma unroll
            for (int k = 0; k < 4; ++k)
                lds64[k * 1024 + tid] =
                    sk_aload_u64((const unsigned long long*)hbG + k * 1024 + tid);
            __syncthreads();
            const int p   = wave >> 2;
            const int seg = wave & 3;
            const int row0 = grow0 + p * 2;
            float hbr[32];
            #pragma unroll
            for (int t = 0; t < 8; ++t) {
                const float4 v =
                    *(const float4*)&lds_hb[(seg * 512 + t * 64 + lane) * 4];
                hbr[t * 4 + 0] = v.x; hbr[t * 4 + 1] = v.y;
                hbr[t * 4 + 2] = v.z; hbr[t * 4 + 3] = v.w;
            }
            const uint4* qp0 = (const uint4*)(QT8 + (size_t)row0 * N_PTS);
            const uint4* qp1 = (const uint4*)(QT8 + (size_t)(row0 + 1) * N_PTS);
            const uint4 a0 = qp0[seg * 128 + lane * 2];
            const uint4 a1 = qp0[seg * 128 + lane * 2 + 1];
            const uint4 b0 = qp1[seg * 128 + lane * 2];
            const uint4 b1 = qp1[seg * 128 + lane * 2 + 1];
            float m0, s0, m1, s1;
            sk_lse32(a0, a1, hbr, m0, s0);
            sk_lse32(b0, b1, hbr, m1, s1);
            #pragma unroll
            for (int off = 1; off < 64; off <<= 1) {
                float mm = __shfl_xor(m0, off, 64), ss = __shfl_xor(s0, off, 64);
                sk_merge(m0, s0, mm, ss);
                mm = __shfl_xor(m1, off, 64); ss = __shfl_xor(s1, off, 64);
                sk_merge(m1, s1, mm, ss);
            }
            if (lane == 0) {
                mred[p][seg][0] = m0; sred[p][seg][0] = s0;
                mred[p][seg][1] = m1; sred[p][seg][1] = s1;
            }
            __syncthreads();
            if (seg == 0 && lane < 2) {
                float m = mred[p][0][lane], s = sred[p][0][lane];
                #pragma unroll
                for (int g = 1; g < 4; ++g)
                    sk_merge(m, s, mred[p][g][lane], sred[p][g][lane]);
                const int row = row0 + lane;
                sk_astore_f(&hbF[row], LW[N_PTS + row] - (m + __logf(s)));
            }
        }
        sk_gbar(cnt, phase++);
    }

    // ---------------- finalize (block 0, agent-scope reads) ----------------
    if (b == 0) {
        float acc = 0.f;
        for (int r = tid; r < N_PTS; r += 1024)
            acc += h[r] * (sk_aload_f(&FO[r]) + 0.5f * EPS_F * LW[r]);
        for (int j = tid; j < M_PTS; j += 1024)
            acc += hi[j] * EPS_F * (sk_aload_f(&hbF[j]) - 0.5f * LW[N_PTS + j]);
        fred[tid] = acc;
        __syncthreads();
        for (int st = 512; st; st >>= 1) {
            if (tid < st) fred[tid] += fred[tid + st];
            __syncthreads();
        }
        if (tid == 0) out[0] = expf(-fred[0]);
    }
}

// ---------------------------------------------------------------------------
extern "C" void kernel_launch(void* const* d_in, const int* in_sizes, int n_in,
                              void* d_out, int out_size, void* d_ws, size_t ws_size,
                              hipStream_t stream)
{
    const float* dpts = (const float*)d_in[0];
    const float* spts = (const float*)d_in[1];
    const float* h    = (const float*)d_in[2];
    const float* hiw  = (const float*)d_in[3];
    const float* W    = (const float*)d_in[4];
    float* out = (float*)d_out;

    float* XS  = (float*)d_ws;                        // NM
    float* LW  = XS + NM_PTS;                         // NM (la | lb)
    float* HBF = LW + NM_PTS;                         // M
    float* HBG = HBF + M_PTS;                         // N
    float* FO  = HBG + N_PTS;                         // N
    int*   R32 = (int*)(FO + N_PTS);                  // N
    int*   CT  = R32 + N_PTS;                         // 102*160 ints (barriers)
    unsigned short* Db = (unsigned short*)(CT + 102 * CTRL_STRIDE); // NM x D bf16
    unsigned short* Wb = Db + (size_t)NM_PTS * D_DIM;           // D x D bf16
    unsigned short* Xb = Wb + (size_t)D_DIM * D_DIM;            // NM x D bf16
    unsigned short* QTu = Xb + (size_t)NM_PTS * D_DIM;          // M x N u16
    unsigned char*  Q8  = (unsigned char*)(QTu + (size_t)M_PTS * N_PTS); // N x M u8
    unsigned char*  QT8 = Q8 + (size_t)N_PTS * M_PTS;           // M x N u8

    sk_init<<<NM_PTS / 256, 256, 0, stream>>>(h, hiw, LW, HBF, R32, CT);

    sk_cast<<<(size_t)N_PTS * D_DIM / 1024, 256, 0, stream>>>(dpts, Db);
    sk_cast<<<(size_t)M_PTS * D_DIM / 1024, 256, 0, stream>>>(
        spts, Db + (size_t)N_PTS * D_DIM);
    sk_cast<<<(size_t)D_DIM * D_DIM / 1024, 256, 0, stream>>>(W, Wb);

    sk_mfma<0><<<dim3(D_DIM / 128, NM_PTS / 128), 256, 0, stream>>>(
        Db, Wb, Xb, nullptr, nullptr, nullptr, nullptr);

    sk_row_norms<<<NM_PTS / 4, 256, 0, stream>>>(Xb, XS);

    sk_mfma<1><<<dim3(M_PTS / 128, N_PTS / 128), 256, 0, stream>>>(
        Xb, Xb + (size_t)N_PTS * D_DIM, nullptr, QTu, R32, XS, XS + N_PTS);

    sk_transq<<<dim3(M_PTS / 64, N_PTS / 64), 256, 0, stream>>>(QTu, R32, Q8);
    sk_requant_qt<<<(size_t)M_PTS * N_PTS / 4096, 256, 0, stream>>>(QTu, R32, QT8);

    {
        void* args[] = { (void*)&Q8, (void*)&QT8, (void*)&LW, (void*)&R32,
                         (void*)&HBF, (void*)&HBG, (void*)&FO,
                         (void*)&h, (void*)&hiw, (void*)&CT, (void*)&out };
        hipLaunchCooperativeKernel(sk_sink_pers, dim3(PERS_BLOCKS), dim3(1024),
                                   args, 0, stream);
    }
}